// Round 3
// baseline (461.039 us; speedup 1.0000x reference)
//
#include <hip/hip_runtime.h>
#include <hip/hip_bf16.h>
#include <cstdint>
#include <cstddef>

#define BB 16
#define TT 8192
#define DD 512
#define NHEAD 8
#define NKV 2
#define HD 64
#define KVD 128
#define SCALE 0.125f

#define MCH 64               // rows per GEMM tile
#define NTILE 2              // tiles per block
#define CHROWS (MCH * NTILE) // 128 rows per block
#define NCHUNK (TT / CHROWS) // 64
#define BK 64
#define NSTEP (DD / BK)      // 8

typedef __attribute__((ext_vector_type(8))) short bf16x8;
typedef __attribute__((ext_vector_type(4))) float f32x4;

// workspace float offsets (same as round 2, 4.75 MB)
#define WS_Q      0                    // 16*512
#define WS_WBT    8192                 // 256*512 u16 = 65536 floats
#define WS_OPART  73728                // 16*64*8*64 = 524288
#define WS_ML     598016               // 16*64*8*2  = 16384
#define WS_H      614400               // 16*1024
#define WS_APART  630784               // 16*16*2048 = 524288
#define WS_ACT    1155072              // 16*2048

__device__ __forceinline__ ushort f2bf(float f) {
    uint u = __builtin_bit_cast(uint, f);
    u += 0x7fffu + ((u >> 16) & 1u);
    return (ushort)(u >> 16);
}
__device__ __forceinline__ uint pack2(float a, float b) {
    return ((uint)f2bf(b) << 16) | f2bf(a);
}
__device__ __forceinline__ float bf1(ushort s) {
    return __builtin_bit_cast(float, (uint)s << 16);
}
__device__ __forceinline__ float bflo(uint u) {
    return __builtin_bit_cast(float, u << 16);
}
__device__ __forceinline__ float bfhi(uint u) {
    return __builtin_bit_cast(float, u & 0xffff0000u);
}

// ---- K0: fused weight pre-pack (fragment order) + q projection -------------
// blocks 0..63 : pack Wk|Wv into per-fragment contiguous bf16 chunks:
//   frag = w*64 + s*8 + kk*4 + nt ; elem (lane,e):
//   col = w*64+nt*16+(lane&15), k = s*64+kk*32+(lane>>4)*8+e
//   wbt2[frag*512 + lane*8 + e] = bf16(Wcat[k][col])
// blocks 64..79: q = query @ Wq for b = blockIdx-64
__global__ __launch_bounds__(256) void k_prep(const float* __restrict__ Wk,
                                              const float* __restrict__ Wv,
                                              const float* __restrict__ query,
                                              const float* __restrict__ Wq,
                                              ushort* __restrict__ wbt2,
                                              float* __restrict__ wsq) {
    const int t = threadIdx.x;
    if (blockIdx.x < 64) {
        const int slot = blockIdx.x * 256 + t;
        const int frag = slot >> 6, lane = slot & 63;
        const int w = frag >> 6, s = (frag >> 3) & 7, kk = (frag >> 2) & 1, nt = frag & 3;
        const int col = w * 64 + nt * 16 + (lane & 15);
        const int kbase = s * 64 + kk * 32 + (lane >> 4) * 8;
        const float* W = (col < KVD) ? (Wk + col) : (Wv + (col - KVD));
#pragma unroll
        for (int e = 0; e < 8; ++e)
            wbt2[(size_t)frag * 512 + lane * 8 + e] = f2bf(W[(size_t)(kbase + e) * KVD]);
    } else {
        __shared__ float qrow[DD];
        const int b = blockIdx.x - 64;
        qrow[t] = query[b * DD + t];
        qrow[t + 256] = query[b * DD + t + 256];
        __syncthreads();
        float a0 = 0.f, a1 = 0.f;
#pragma unroll 8
        for (int d = 0; d < DD; ++d) {
            const float q = qrow[d];
            a0 = fmaf(q, Wq[(size_t)d * DD + t], a0);
            a1 = fmaf(q, Wq[(size_t)d * DD + t + 256], a1);
        }
        wsq[b * DD + t] = a0;
        wsq[b * DD + t + 256] = a1;
    }
}

// ---- K2: MFMA K/V projection + flash-decode attention ----------------------
// grid (NCHUNK, BB), 256 threads = 4 waves, wave tile 64 rows x 64 cols
__global__ __launch_bounds__(256, 4) void k_attn(const float* __restrict__ enc,
                                                 const ushort* __restrict__ wbt2,
                                                 const float* __restrict__ wsq,
                                                 float* __restrict__ o_part,
                                                 float* __restrict__ ml) {
    __shared__ __align__(16) char smem[33024];   // kvl [64][258]u16; A0|A1 (8K each) alias
    __shared__ float sc[NHEAD * MCH];            // 2 KB
    __shared__ float qs[DD];                     // 2 KB

    const int tid = threadIdx.x;
    const int chunk = blockIdx.x, b = blockIdx.y;
    const int lane = tid & 63, w = tid >> 6;

    qs[tid] = wsq[b * DD + tid] * SCALE;
    qs[tid + 256] = wsq[b * DD + tid + 256] * SCALE;

    char* const A0 = smem;
    char* const A1 = smem + 8192;
    ushort* const kvl = (ushort*)smem;

    const float* encb = enc + ((size_t)b * TT + (size_t)chunk * CHROWS) * DD;
    const ushort* wfr = wbt2 + (size_t)w * 64 * 512 + (size_t)lane * 8;

    const int ar = tid >> 4;             // staging rows ar + p*16
    const int akq = (tid & 15) * 4;      // staging k offset (floats)

    const int h0 = w * 2;                // this wave's two heads
    const int kvh = h0 >> 2;

    f32x4 acc[4][4];
#pragma unroll
    for (int i = 0; i < 4; ++i)
#pragma unroll
        for (int j = 0; j < 4; ++j) acc[i][j] = (f32x4){0.f, 0.f, 0.f, 0.f};

    float m_h[2] = {-1e30f, -1e30f}, l_h[2] = {0.f, 0.f}, o_h[2] = {0.f, 0.f};
    float4 e[4];

#define LOAD_ENC(tt, ss)                                                              \
    {                                                                                 \
        _Pragma("unroll") for (int p = 0; p < 4; ++p)                                 \
            e[p] = *(const float4*)(encb + (size_t)((tt) * MCH + ar + p * 16) * DD +  \
                                    (ss) * BK + akq);                                 \
    }
#define WRITE_A(Abuf)                                                                 \
    {                                                                                 \
        _Pragma("unroll") for (int p = 0; p < 4; ++p) {                               \
            const int row = ar + p * 16;                                              \
            uint2 u;                                                                  \
            u.x = pack2(e[p].x, e[p].y);                                              \
            u.y = pack2(e[p].z, e[p].w);                                              \
            *(uint2*)((Abuf) + row * 128 + ((akq * 2) ^ ((row & 7) << 4))) = u;       \
        }                                                                             \
    }

    LOAD_ENC(0, 0);

    for (int tile = 0; tile < NTILE; ++tile) {
        __syncthreads();                 // prev epilogue's kvl reads done (or nop)
        WRITE_A(A0);                     // e holds (tile, 0)
        LOAD_ENC(tile, 1);

        for (int s = 0; s < NSTEP; ++s) {
            const int cur = s & 1;
            char* const Ac = cur ? A1 : A0;
            char* const An = cur ? A0 : A1;
            // B fragments straight from L2 (coalesced 1KB chunks), pre-barrier issue
            bf16x8 bfr[2][4];
#pragma unroll
            for (int kk = 0; kk < 2; ++kk)
#pragma unroll
                for (int nt = 0; nt < 4; ++nt)
                    bfr[kk][nt] = *(const bf16x8*)(wfr + (size_t)(s * 8 + kk * 4 + nt) * 512);
            __syncthreads();             // A[cur] visible; compute on An (s-1) done
            if (s + 1 < NSTEP) {
                WRITE_A(An);             // e holds (tile, s+1)
                if (s + 2 < NSTEP) LOAD_ENC(tile, s + 2)
                else if (tile + 1 < NTILE) LOAD_ENC(tile + 1, 0)
            }
#pragma unroll
            for (int kk = 0; kk < 2; ++kk) {
                const int kbyte = kk * 64 + (lane >> 4) * 16;
#pragma unroll
                for (int rt = 0; rt < 4; ++rt) {
                    const int row = rt * 16 + (lane & 15);
                    const bf16x8 af =
                        *(const bf16x8*)(Ac + row * 128 + (kbyte ^ ((row & 7) << 4)));
#pragma unroll
                    for (int nt = 0; nt < 4; ++nt)
                        acc[rt][nt] = __builtin_amdgcn_mfma_f32_16x16x32_bf16(
                            af, bfr[kk][nt], acc[rt][nt], 0, 0, 0);
                }
            }
        }

        // ---- epilogue for this tile ----
        __syncthreads();                 // all MFMA reads of A bufs done
#pragma unroll
        for (int rt = 0; rt < 4; ++rt)
#pragma unroll
            for (int nt = 0; nt < 4; ++nt) {
                const int col = w * 64 + nt * 16 + (lane & 15);
#pragma unroll
                for (int j = 0; j < 4; ++j) {
                    const int row = rt * 16 + (lane >> 4) * 4 + j;
                    kvl[row * 258 + col] = f2bf(acc[rt][nt][j]);
                    acc[rt][nt][j] = 0.f;
                }
            }
        __syncthreads();

        // scores for heads h0, h0+1 (row = lane)
        {
            const float* qh0 = qs + h0 * HD;
            const float* qh1 = qs + (h0 + 1) * HD;
            const uint* kr = (const uint*)(kvl + lane * 258 + kvh * HD);
            float s0 = 0.f, s1 = 0.f;
#pragma unroll
            for (int d2 = 0; d2 < 32; ++d2) {
                const uint u = kr[d2];
                const float klo = bflo(u), khi = bfhi(u);
                s0 = fmaf(klo, qh0[2 * d2], s0);
                s0 = fmaf(khi, qh0[2 * d2 + 1], s0);
                s1 = fmaf(klo, qh1[2 * d2], s1);
                s1 = fmaf(khi, qh1[2 * d2 + 1], s1);
            }
            sc[h0 * MCH + lane] = s0;
            sc[(h0 + 1) * MCH + lane] = s1;
        }
        __syncthreads();

        // online softmax + PV (d = lane, both heads share V rows)
        {
            float mx0 = -1e30f, mx1 = -1e30f;
#pragma unroll 8
            for (int r = 0; r < MCH; ++r) {
                mx0 = fmaxf(mx0, sc[h0 * MCH + r]);
                mx1 = fmaxf(mx1, sc[(h0 + 1) * MCH + r]);
            }
            const float mn0 = fmaxf(m_h[0], mx0), mn1 = fmaxf(m_h[1], mx1);
            const float rs0 = __expf(m_h[0] - mn0), rs1 = __expf(m_h[1] - mn1);
            o_h[0] *= rs0; l_h[0] *= rs0;
            o_h[1] *= rs1; l_h[1] *= rs1;
            const ushort* vcol = kvl + KVD + kvh * HD + lane;
#pragma unroll 4
            for (int r = 0; r < MCH; ++r) {
                const float vv = bf1(vcol[r * 258]);
                const float p0 = __expf(sc[h0 * MCH + r] - mn0);
                const float p1 = __expf(sc[(h0 + 1) * MCH + r] - mn1);
                l_h[0] += p0; o_h[0] = fmaf(p0, vv, o_h[0]);
                l_h[1] += p1; o_h[1] = fmaf(p1, vv, o_h[1]);
            }
            m_h[0] = mn0; m_h[1] = mn1;
        }
    }

#pragma unroll
    for (int hh = 0; hh < 2; ++hh) {
        const size_t base = ((size_t)b * NCHUNK + chunk) * NHEAD + h0 + hh;
        o_part[base * HD + lane] = o_h[hh];
        if (lane == 0) { ml[base * 2] = m_h[hh]; ml[base * 2 + 1] = l_h[hh]; }
    }
#undef LOAD_ENC
#undef WRITE_A
}

// ---- K3: combine chunk partials -> context, build h = [ctx|query] ----------
__global__ __launch_bounds__(512) void k_reduce(const float* __restrict__ o_part,
                                                const float* __restrict__ ml,
                                                const float* __restrict__ query,
                                                float* __restrict__ hvec) {
    const int b = blockIdx.x, t = threadIdx.x;
    const int h = t >> 6, d = t & 63;
    float M = -1e30f, L = 0.f, O = 0.f;
    for (int i = 0; i < NCHUNK; ++i) {
        const size_t base = ((size_t)b * NCHUNK + i) * NHEAD + h;
        const float mi = ml[base * 2], li = ml[base * 2 + 1];
        const float oi = o_part[base * HD + d];
        const float Mn = fmaxf(M, mi);
        const float f1 = __expf(M - Mn), f2 = __expf(mi - Mn);
        L = L * f1 + li * f2;
        O = O * f1 + oi * f2;
        M = Mn;
    }
    hvec[b * 1024 + h * HD + d] = O / L;
    hvec[b * 1024 + 512 + t] = query[b * DD + t];
}

// ---- K4: MLP1 partial GEMM h @ W1 (16-way i-split) -------------------------
__global__ __launch_bounds__(256) void k_mlp1(const float* __restrict__ hvec,
                                              const float* __restrict__ W1,
                                              float* __restrict__ apart) {
    const int jb = blockIdx.x, ib = blockIdx.y;
    const int j = jb * 256 + threadIdx.x;
    float acc[BB];
#pragma unroll
    for (int b = 0; b < BB; ++b) acc[b] = 0.f;
    for (int i0 = ib * 64; i0 < ib * 64 + 64; i0 += 4) {
        const float w0 = W1[(size_t)(i0 + 0) * 2048 + j];
        const float w1 = W1[(size_t)(i0 + 1) * 2048 + j];
        const float w2 = W1[(size_t)(i0 + 2) * 2048 + j];
        const float w3 = W1[(size_t)(i0 + 3) * 2048 + j];
#pragma unroll
        for (int b = 0; b < BB; ++b) {
            const float* hb = hvec + b * 1024 + i0;
            acc[b] = fmaf(hb[0], w0, acc[b]);
            acc[b] = fmaf(hb[1], w1, acc[b]);
            acc[b] = fmaf(hb[2], w2, acc[b]);
            acc[b] = fmaf(hb[3], w3, acc[b]);
        }
    }
#pragma unroll
    for (int b = 0; b < BB; ++b)
        apart[((size_t)ib * BB + b) * 2048 + j] = acc[b];
}

// ---- K4b: sum i-partials + SiLU --------------------------------------------
__global__ __launch_bounds__(256) void k_silu(const float* __restrict__ apart,
                                              float* __restrict__ act) {
    const int idx = blockIdx.x * 256 + threadIdx.x;
    float s = 0.f;
#pragma unroll
    for (int ib = 0; ib < 16; ++ib) s += apart[(size_t)ib * BB * 2048 + idx];
    act[idx] = s / (1.f + __expf(-s));
}

// ---- K5: MLP2 act @ W2 -> out ----------------------------------------------
__global__ __launch_bounds__(256) void k_mlp2(const float* __restrict__ act,
                                              const float* __restrict__ W2,
                                              float* __restrict__ out) {
    const int b = blockIdx.y;
    const int d = blockIdx.x * 256 + threadIdx.x;
    const float* ab = act + b * 2048;
    float acc = 0.f;
    for (int j0 = 0; j0 < 2048; j0 += 4) {
        acc = fmaf(ab[j0 + 0], W2[(size_t)(j0 + 0) * 512 + d], acc);
        acc = fmaf(ab[j0 + 1], W2[(size_t)(j0 + 1) * 512 + d], acc);
        acc = fmaf(ab[j0 + 2], W2[(size_t)(j0 + 2) * 512 + d], acc);
        acc = fmaf(ab[j0 + 3], W2[(size_t)(j0 + 3) * 512 + d], acc);
    }
    out[b * DD + d] = acc;
}

extern "C" void kernel_launch(void* const* d_in, const int* in_sizes, int n_in,
                              void* d_out, int out_size, void* d_ws, size_t ws_size,
                              hipStream_t stream) {
    const float* query = (const float*)d_in[0];
    const float* enc   = (const float*)d_in[1];
    const float* Wq    = (const float*)d_in[2];
    const float* Wk    = (const float*)d_in[3];
    const float* Wv    = (const float*)d_in[4];
    const float* W1    = (const float*)d_in[5];
    const float* W2    = (const float*)d_in[6];
    float* ws  = (float*)d_ws;
    float* out = (float*)d_out;
    ushort* wbt2 = (ushort*)(ws + WS_WBT);

    k_prep<<<dim3(80), dim3(256), 0, stream>>>(Wk, Wv, query, Wq, wbt2, ws + WS_Q);
    k_attn<<<dim3(NCHUNK, BB), dim3(256), 0, stream>>>(enc, wbt2, ws + WS_Q,
                                                       ws + WS_OPART, ws + WS_ML);
    k_reduce<<<dim3(BB), dim3(512), 0, stream>>>(ws + WS_OPART, ws + WS_ML, query, ws + WS_H);
    k_mlp1<<<dim3(8, 16), dim3(256), 0, stream>>>(ws + WS_H, W1, ws + WS_APART);
    k_silu<<<dim3(128), dim3(256), 0, stream>>>(ws + WS_APART, ws + WS_ACT);
    k_mlp2<<<dim3(2, BB), dim3(256), 0, stream>>>(ws + WS_ACT, W2, out);
}

// Round 5
// 323.654 us; speedup vs baseline: 1.4245x; 1.4245x over previous
//
#include <hip/hip_runtime.h>
#include <hip/hip_bf16.h>
#include <cstdint>
#include <cstddef>

#define BB 16
#define TT 8192
#define DD 512
#define NHEAD 8
#define NKV 2
#define HD 64
#define KVD 128
#define SCALE 0.125f

#define CHROWS 128           // enc rows per block
#define NCHUNK (TT / CHROWS) // 64
#define BK 32
#define NSTEP (DD / BK)      // 16

typedef __attribute__((ext_vector_type(8))) short bf16x8;
typedef __attribute__((ext_vector_type(4))) float f32x4;

// workspace float offsets (4.75 MB)
#define WS_Q      0                    // 16*512
#define WS_WBT    8192                 // 256*512 u16 = 65536 floats
#define WS_OPART  73728                // 16*64*8*64 = 524288
#define WS_ML     598016               // 16*64*8*2  = 16384
#define WS_H      614400               // 16*1024
#define WS_APART  630784               // 16*16*2048 = 524288
#define WS_ACT    1155072              // 16*2048

__device__ __forceinline__ ushort f2bf(float f) {
    uint u = __builtin_bit_cast(uint, f);
    u += 0x7fffu + ((u >> 16) & 1u);
    return (ushort)(u >> 16);
}
__device__ __forceinline__ uint pack2(float a, float b) {
    return ((uint)f2bf(b) << 16) | f2bf(a);
}
__device__ __forceinline__ float bf1(ushort s) {
    return __builtin_bit_cast(float, (uint)s << 16);
}
__device__ __forceinline__ float bflo(uint u) {
    return __builtin_bit_cast(float, u << 16);
}
__device__ __forceinline__ float bfhi(uint u) {
    return __builtin_bit_cast(float, u & 0xffff0000u);
}
__device__ __forceinline__ void gload_lds16(const void* g, void* l) {
    __builtin_amdgcn_global_load_lds((const __attribute__((address_space(1))) uint32_t*)g,
                                     (__attribute__((address_space(3))) uint32_t*)l, 16, 0, 0);
}

// ---- K0: fused weight pre-pack (GLL-linear, read-XOR pre-applied) + q-proj -
// wbt3 element G: step=G>>13, P=G&8191, col=P>>5, ec=P&31,
//   stored value = bf16( Wcat[ step*32 + (ec ^ ((col&3)<<3)) ][ col ] )
// so k_attn can GLL 16KB linearly and ds_read with the same XOR.
__global__ __launch_bounds__(256) void k_prep(const float* __restrict__ Wk,
                                              const float* __restrict__ Wv,
                                              const float* __restrict__ query,
                                              const float* __restrict__ Wq,
                                              ushort* __restrict__ wbt3,
                                              float* __restrict__ wsq) {
    const int t = threadIdx.x;
    if (blockIdx.x < 64) {
        const int G0 = blockIdx.x * 2048 + t * 8;
#pragma unroll
        for (int i = 0; i < 8; ++i) {
            const int G = G0 + i;
            const int step = G >> 13, P = G & 8191;
            const int col = P >> 5, ec = P & 31;
            const int k = step * 32 + (ec ^ ((col & 3) << 3));
            const float v = (col < KVD) ? Wk[(size_t)k * KVD + col]
                                        : Wv[(size_t)k * KVD + (col - KVD)];
            wbt3[G] = f2bf(v);
        }
    } else {
        __shared__ float qrow[DD];
        const int b = blockIdx.x - 64;
        qrow[t] = query[b * DD + t];
        qrow[t + 256] = query[b * DD + t + 256];
        __syncthreads();
        float a0 = 0.f, a1 = 0.f;
#pragma unroll 8
        for (int d = 0; d < DD; ++d) {
            const float q = qrow[d];
            a0 = fmaf(q, Wq[(size_t)d * DD + t], a0);
            a1 = fmaf(q, Wq[(size_t)d * DD + t + 256], a1);
        }
        wsq[b * DD + t] = a0;
        wsq[b * DD + t + 256] = a1;
    }
}

// ---- K2: MFMA K/V projection + flash-decode attention ----------------------
// grid (NCHUNK, BB), 512 threads = 8 waves (2 wm x 4 wn), wave tile 64x64
// LDS: A dbuf 2x8K + B dbuf 2x16K = 48K (kvt [128][130]=33K aliases) +sc4K+qs2K
__global__ __launch_bounds__(512, 4) void k_attn(const float* __restrict__ enc,
                                                 const ushort* __restrict__ wbt3,
                                                 const float* __restrict__ wsq,
                                                 float* __restrict__ o_part,
                                                 float* __restrict__ ml) {
    __shared__ __align__(16) char smem[49152];
    __shared__ float sc[NHEAD * CHROWS];     // 4 KB
    __shared__ float qs[DD];                 // 2 KB

    const int tid = threadIdx.x;
    const int chunk = blockIdx.x, b = blockIdx.y;
    const int lane = tid & 63, w = tid >> 6;
    const int wm = w >> 2, wn = w & 3;

    qs[tid] = wsq[b * DD + tid] * SCALE;

    char* const A0 = smem;
    char* const A1 = smem + 8192;
    char* const B0 = smem + 16384;
    char* const B1 = smem + 32768;
    ushort* const kvt = (ushort*)smem;       // [128][130] bf16, aliased

    const float* encb = enc + ((size_t)b * TT + (size_t)chunk * CHROWS) * DD;

    const int ar = tid >> 3;                 // staging rows ar, ar+64
    const int ek = (tid & 7) * 4;            // element offset 0..28

    f32x4 acc[4][4];
#pragma unroll
    for (int i = 0; i < 4; ++i)
#pragma unroll
        for (int j = 0; j < 4; ++j) acc[i][j] = (f32x4){0.f, 0.f, 0.f, 0.f};

    float4 e[2];

#define LOAD_ENC(ss)                                                                  \
    {                                                                                 \
        _Pragma("unroll") for (int p = 0; p < 2; ++p)                                 \
            e[p] = *(const float4*)(encb + (size_t)(ar + p * 64) * DD + (ss) * BK + ek); \
    }
#define WRITE_A(Abuf)                                                                 \
    {                                                                                 \
        _Pragma("unroll") for (int p = 0; p < 2; ++p) {                               \
            const int row = ar + p * 64;                                              \
            uint2 u;                                                                  \
            u.x = pack2(e[p].x, e[p].y);                                              \
            u.y = pack2(e[p].z, e[p].w);                                              \
            *(uint2*)((Abuf) + row * 64 + (ek ^ ((row & 3) << 3)) * 2) = u;           \
        }                                                                             \
    }
#define GLL_B(Bbuf, ss)                                                               \
    {                                                                                 \
        _Pragma("unroll") for (int j = 0; j < 2; ++j)                                 \
            gload_lds16(wbt3 + (size_t)(ss) * 8192 + (j * 8 + w) * 512 + lane * 8,    \
                        (Bbuf) + (j * 8 + w) * 1024);                                 \
    }

    // prologue: stage step 0, prefetch enc for step 1
    LOAD_ENC(0);
    GLL_B(B0, 0);
    WRITE_A(A0);
    LOAD_ENC(1);

    for (int s = 0; s < NSTEP; ++s) {
        const int cur = s & 1;
        char* const Ac = cur ? A1 : A0;
        char* const Bc = cur ? B1 : B0;
        char* const An = cur ? A0 : A1;
        char* const Bn = cur ? B0 : B1;
        __syncthreads();                     // A[cur]/B[cur] staged & visible
        if (s + 1 < NSTEP) {
            GLL_B(Bn, s + 1);
            WRITE_A(An);                     // e holds step s+1
            if (s + 2 < NSTEP) LOAD_ENC(s + 2);
        }
        // compute on cur
        bf16x8 bfr[4];
#pragma unroll
        for (int nt = 0; nt < 4; ++nt) {
            const int col = wn * 64 + nt * 16 + (lane & 15);
            const int eo = ((lane >> 4) * 8) ^ ((col & 3) << 3);
            bfr[nt] = *(const bf16x8*)(Bc + col * 64 + eo * 2);
        }
#pragma unroll
        for (int rt = 0; rt < 4; ++rt) {
            const int row = wm * 64 + rt * 16 + (lane & 15);
            const int eo = ((lane >> 4) * 8) ^ ((row & 3) << 3);
            const bf16x8 af = *(const bf16x8*)(Ac + row * 64 + eo * 2);
#pragma unroll
            for (int nt = 0; nt < 4; ++nt)
                acc[rt][nt] = __builtin_amdgcn_mfma_f32_16x16x32_bf16(
                    af, bfr[nt], acc[rt][nt], 0, 0, 0);
        }
    }

    const int h = w, kvh = h >> 2;

    // ---- two-pass epilogue: pass 1 = K tile ----
    __syncthreads();
    if (wn < 2) {
#pragma unroll
        for (int rt = 0; rt < 4; ++rt)
#pragma unroll
            for (int nt = 0; nt < 4; ++nt) {
                const int col = wn * 64 + nt * 16 + (lane & 15);
#pragma unroll
                for (int j = 0; j < 4; ++j) {
                    const int row = wm * 64 + rt * 16 + (lane >> 4) * 4 + j;
                    kvt[row * 130 + col] = f2bf(acc[rt][nt][j]);
                }
            }
    }
    __syncthreads();

    // scores: wave w == head h; rows lane, lane+64
    {
        const float* qh = qs + h * HD;
#pragma unroll
        for (int rr = 0; rr < 2; ++rr) {
            const int r = lane + rr * 64;
            const uint* kr = (const uint*)(kvt + r * 130 + kvh * HD);
            float s = 0.f;
#pragma unroll
            for (int d2 = 0; d2 < 32; ++d2) {
                const uint u = kr[d2];
                s = fmaf(bflo(u), qh[2 * d2], s);
                s = fmaf(bfhi(u), qh[2 * d2 + 1], s);
            }
            sc[h * CHROWS + r] = s;
        }
    }
    __syncthreads();                         // scores done, K reads done

    // ---- pass 2: V tile overwrites the same LDS ----
    if (wn >= 2) {
#pragma unroll
        for (int rt = 0; rt < 4; ++rt)
#pragma unroll
            for (int nt = 0; nt < 4; ++nt) {
                const int col = (wn - 2) * 64 + nt * 16 + (lane & 15);
#pragma unroll
                for (int j = 0; j < 4; ++j) {
                    const int row = wm * 64 + rt * 16 + (lane >> 4) * 4 + j;
                    kvt[row * 130 + col] = f2bf(acc[rt][nt][j]);
                }
            }
    }
    __syncthreads();

    // softmax + PV: thread (h = w, d = lane)
    {
        float m = -1e30f;
#pragma unroll 8
        for (int r = 0; r < CHROWS; ++r) m = fmaxf(m, sc[h * CHROWS + r]);
        float l = 0.f, o = 0.f;
        const ushort* vcol = kvt + kvh * HD + lane;
#pragma unroll 4
        for (int r = 0; r < CHROWS; ++r) {
            const float p = __expf(sc[h * CHROWS + r] - m);
            l += p;
            o = fmaf(p, bf1(vcol[r * 130]), o);
        }
        const size_t base = ((size_t)b * NCHUNK + chunk) * NHEAD + h;
        o_part[base * HD + lane] = o;
        if (lane == 0) { ml[base * 2] = m; ml[base * 2 + 1] = l; }
    }
#undef LOAD_ENC
#undef WRITE_A
#undef GLL_B
}

// ---- K3: combine chunk partials -> context, build h = [ctx|query] ----------
__global__ __launch_bounds__(512) void k_reduce(const float* __restrict__ o_part,
                                                const float* __restrict__ ml,
                                                const float* __restrict__ query,
                                                float* __restrict__ hvec) {
    const int b = blockIdx.x, t = threadIdx.x;
    const int h = t >> 6, d = t & 63;
    float M = -1e30f, L = 0.f, O = 0.f;
    for (int i = 0; i < NCHUNK; ++i) {
        const size_t base = ((size_t)b * NCHUNK + i) * NHEAD + h;
        const float mi = ml[base * 2], li = ml[base * 2 + 1];
        const float oi = o_part[base * HD + d];
        const float Mn = fmaxf(M, mi);
        const float f1 = __expf(M - Mn), f2 = __expf(mi - Mn);
        L = L * f1 + li * f2;
        O = O * f1 + oi * f2;
        M = Mn;
    }
    hvec[b * 1024 + h * HD + d] = O / L;
    hvec[b * 1024 + 512 + t] = query[b * DD + t];
}

// ---- K4: MLP1 partial GEMM h @ W1 (16-way i-split) -------------------------
__global__ __launch_bounds__(256) void k_mlp1(const float* __restrict__ hvec,
                                              const float* __restrict__ W1,
                                              float* __restrict__ apart) {
    const int jb = blockIdx.x, ib = blockIdx.y;
    const int j = jb * 256 + threadIdx.x;
    float acc[BB];
#pragma unroll
    for (int b = 0; b < BB; ++b) acc[b] = 0.f;
    for (int i0 = ib * 64; i0 < ib * 64 + 64; i0 += 4) {
        const float w0 = W1[(size_t)(i0 + 0) * 2048 + j];
        const float w1 = W1[(size_t)(i0 + 1) * 2048 + j];
        const float w2 = W1[(size_t)(i0 + 2) * 2048 + j];
        const float w3 = W1[(size_t)(i0 + 3) * 2048 + j];
#pragma unroll
        for (int b = 0; b < BB; ++b) {
            const float* hb = hvec + b * 1024 + i0;
            acc[b] = fmaf(hb[0], w0, acc[b]);
            acc[b] = fmaf(hb[1], w1, acc[b]);
            acc[b] = fmaf(hb[2], w2, acc[b]);
            acc[b] = fmaf(hb[3], w3, acc[b]);
        }
    }
#pragma unroll
    for (int b = 0; b < BB; ++b)
        apart[((size_t)ib * BB + b) * 2048 + j] = acc[b];
}

// ---- K4b: sum i-partials + SiLU --------------------------------------------
__global__ __launch_bounds__(256) void k_silu(const float* __restrict__ apart,
                                              float* __restrict__ act) {
    const int idx = blockIdx.x * 256 + threadIdx.x;
    float s = 0.f;
#pragma unroll
    for (int ib = 0; ib < 16; ++ib) s += apart[(size_t)ib * BB * 2048 + idx];
    act[idx] = s / (1.f + __expf(-s));
}

// ---- K5: MLP2 act @ W2 -> out ----------------------------------------------
__global__ __launch_bounds__(256) void k_mlp2(const float* __restrict__ act,
                                              const float* __restrict__ W2,
                                              float* __restrict__ out) {
    const int b = blockIdx.y;
    const int d = blockIdx.x * 256 + threadIdx.x;
    const float* ab = act + b * 2048;
    float acc = 0.f;
    for (int j0 = 0; j0 < 2048; j0 += 4) {
        acc = fmaf(ab[j0 + 0], W2[(size_t)(j0 + 0) * 512 + d], acc);
        acc = fmaf(ab[j0 + 1], W2[(size_t)(j0 + 1) * 512 + d], acc);
        acc = fmaf(ab[j0 + 2], W2[(size_t)(j0 + 2) * 512 + d], acc);
        acc = fmaf(ab[j0 + 3], W2[(size_t)(j0 + 3) * 512 + d], acc);
    }
    out[b * DD + d] = acc;
}

extern "C" void kernel_launch(void* const* d_in, const int* in_sizes, int n_in,
                              void* d_out, int out_size, void* d_ws, size_t ws_size,
                              hipStream_t stream) {
    const float* query = (const float*)d_in[0];
    const float* enc   = (const float*)d_in[1];
    const float* Wq    = (const float*)d_in[2];
    const float* Wk    = (const float*)d_in[3];
    const float* Wv    = (const float*)d_in[4];
    const float* W1    = (const float*)d_in[5];
    const float* W2    = (const float*)d_in[6];
    float* ws  = (float*)d_ws;
    float* out = (float*)d_out;
    ushort* wbt3 = (ushort*)(ws + WS_WBT);

    k_prep<<<dim3(80), dim3(256), 0, stream>>>(Wk, Wv, query, Wq, wbt3, ws + WS_Q);
    k_attn<<<dim3(NCHUNK, BB), dim3(512), 0, stream>>>(enc, wbt3, ws + WS_Q,
                                                       ws + WS_OPART, ws + WS_ML);
    k_reduce<<<dim3(BB), dim3(512), 0, stream>>>(ws + WS_OPART, ws + WS_ML, query, ws + WS_H);
    k_mlp1<<<dim3(8, 16), dim3(256), 0, stream>>>(ws + WS_H, W1, ws + WS_APART);
    k_silu<<<dim3(128), dim3(256), 0, stream>>>(ws + WS_APART, ws + WS_ACT);
    k_mlp2<<<dim3(2, BB), dim3(256), 0, stream>>>(ws + WS_ACT, W2, out);
}